// Round 6
// baseline (35.450 us; speedup 1.0000x reference)
//
#include <hip/hip_runtime.h>

// E[b] = sum_n h_n^T (0.5*I + 0.1*W) h_n  — single-kernel streaming reduction.
// B=64, N=65536, I=8. h: (B,N,I) f32, W: (8,8) f32.
// Symmetric fold: e = sum_i h_i * (c_i*h_i + sum_{j>i} s_ij*h_j).
// Plain cached float4 loads (nt loads measured 2x slower, round 4).
// One f32 atomicAdd per block into out[b]; d_out zeroed by a memset graph node.

#define B_ 64
#define N_ 65536
#define I_ 8
#define BPB 32                        // blocks per batch
#define THREADS 256
#define NPB (N_ / BPB)                // 2048 nodes per block
#define NPT (NPB / THREADS)           // 8 nodes per thread

__device__ __forceinline__ float uniform_f(float x) {
  return __int_as_float(__builtin_amdgcn_readfirstlane(__float_as_int(x)));
}

__global__ __launch_bounds__(THREADS) void energy_kernel(
    const float* __restrict__ h, const float* __restrict__ W,
    float* __restrict__ out) {
  const int blk = blockIdx.x;
  const int b = blk >> 5;             // blk / BPB
  const int chunk = blk & (BPB - 1);  // blk % BPB
  const int t = threadIdx.x;

  // 36 wave-uniform coefficients, forced into SGPRs.
  float c[I_];
  float s[I_][I_];
#pragma unroll
  for (int i = 0; i < I_; ++i) {
    c[i] = uniform_f(0.5f + 0.1f * W[i * I_ + i]);
#pragma unroll
    for (int j = i + 1; j < I_; ++j)
      s[i][j] = uniform_f(0.1f * (W[i * I_ + j] + W[j * I_ + i]));
  }

  const size_t base = (size_t)b * N_ + (size_t)chunk * NPB;
  float acc = 0.0f;

#pragma unroll
  for (int k = 0; k < NPT; ++k) {
    const size_t node = base + (size_t)k * THREADS + (size_t)t;
    const float4* p = reinterpret_cast<const float4*>(h + node * I_);
    float4 a = p[0];
    float4 d = p[1];
    float hv[I_] = {a.x, a.y, a.z, a.w, d.x, d.y, d.z, d.w};
    float e = 0.0f;
#pragma unroll
    for (int i = 0; i < I_; ++i) {
      float ti = c[i] * hv[i];
#pragma unroll
      for (int j = i + 1; j < I_; ++j) ti = fmaf(s[i][j], hv[j], ti);
      e = fmaf(hv[i], ti, e);
    }
    acc += e;
  }

  // Wave(64)-wide shuffle reduction, then cross-wave via LDS.
#pragma unroll
  for (int off = 32; off > 0; off >>= 1)
    acc += __shfl_down(acc, off, 64);

  __shared__ float wsum[THREADS / 64];
  const int wave = t >> 6;
  const int lane = t & 63;
  if (lane == 0) wsum[wave] = acc;
  __syncthreads();
  if (t == 0) {
    float sum = 0.0f;
#pragma unroll
    for (int w = 0; w < THREADS / 64; ++w) sum += wsum[w];
    atomicAdd(&out[b], sum);          // 32 adds per address, device scope
  }
}

extern "C" void kernel_launch(void* const* d_in, const int* in_sizes, int n_in,
                              void* d_out, int out_size, void* d_ws, size_t ws_size,
                              hipStream_t stream) {
  const float* h = (const float*)d_in[0];
  const float* W = (const float*)d_in[1];
  float* out = (float*)d_out;

  (void)hipMemsetAsync(out, 0, B_ * sizeof(float), stream);  // 256 B graph node
  energy_kernel<<<B_ * BPB, THREADS, 0, stream>>>(h, W, out);
}

// Round 7
// 27.986 us; speedup vs baseline: 1.2667x; 1.2667x over previous
//
#include <hip/hip_runtime.h>

// E[b] = sum_n h_n^T (0.5*I + 0.1*W) h_n  — pure streaming reduction.
// B=64, N=65536, I=8. h: (B,N,I) f32, W: (8,8) f32.
// Dense-load variant: every wave load instruction covers a contiguous 1KB
// span (lane l <-> float4 slot base+l). A node's two float4 halves land in
// a lane pair; one shfl_xor(1) exchange reassembles a full node per lane
// (even lanes evaluate node A, odd lanes node B; parity-selected operands,
// wave-uniform code). Two-kernel deterministic reduction (single-kernel +
// memset measured +9us in round 6; nt loads measured 2x in round 4).

#define B_ 64
#define N_ 65536
#define I_ 8
#define BPB 32                        // blocks per batch
#define THREADS 256
#define NPB (N_ / BPB)                // 2048 nodes per block
#define ITERS 8                       // per-wave iterations: 8 * 2KB = 16KB

__device__ __forceinline__ float uniform_f(float x) {
  return __int_as_float(__builtin_amdgcn_readfirstlane(__float_as_int(x)));
}

__device__ __forceinline__ float4 shflx1(float4 v) {
  float4 r;
  r.x = __shfl_xor(v.x, 1, 64);
  r.y = __shfl_xor(v.y, 1, 64);
  r.z = __shfl_xor(v.z, 1, 64);
  r.w = __shfl_xor(v.w, 1, 64);
  return r;
}

__global__ __launch_bounds__(THREADS) void energy_partial_kernel(
    const float* __restrict__ h, const float* __restrict__ W,
    float* __restrict__ partial) {
  const int blk = blockIdx.x;
  const int b = blk >> 5;             // blk / BPB
  const int chunk = blk & (BPB - 1);  // blk % BPB
  const int t = threadIdx.x;
  const int wave = t >> 6;
  const int lane = t & 63;
  const bool evenlane = (lane & 1) == 0;

  // 36 wave-uniform coefficients, forced into SGPRs.
  float c[I_];
  float s[I_][I_];
#pragma unroll
  for (int i = 0; i < I_; ++i) {
    c[i] = uniform_f(0.5f + 0.1f * W[i * I_ + i]);
#pragma unroll
    for (int j = i + 1; j < I_; ++j)
      s[i][j] = uniform_f(0.1f * (W[i * I_ + j] + W[j * I_ + i]));
  }

  // float4-slot base for this block+wave (slot = 16B unit; node = 2 slots).
  const float4* hp = reinterpret_cast<const float4*>(h);
  const size_t slotBase =
      ((size_t)b * N_ + (size_t)chunk * NPB) * 2 + (size_t)wave * (ITERS * 128);

  float acc = 0.0f;

#pragma unroll
  for (int it = 0; it < ITERS; ++it) {
    const size_t sb = slotBase + (size_t)it * 128;
    float4 x = hp[sb + lane];         // dense 1KB: slots [sb, sb+64)
    float4 y = hp[sb + 64 + lane];    // dense 1KB: slots [sb+64, sb+128)
    float4 px = shflx1(x);            // partner's half of node A
    float4 py = shflx1(y);            // partner's half of node B
    // even lane: node A = (x | px); odd lane: node B = (py | y)
    float4 v = evenlane ? x : py;     // lo half
    float4 w = evenlane ? px : y;     // hi half
    float hv[I_] = {v.x, v.y, v.z, v.w, w.x, w.y, w.z, w.w};
    float e = 0.0f;
#pragma unroll
    for (int i = 0; i < I_; ++i) {
      float ti = c[i] * hv[i];
#pragma unroll
      for (int j = i + 1; j < I_; ++j) ti = fmaf(s[i][j], hv[j], ti);
      e = fmaf(hv[i], ti, e);
    }
    acc += e;
  }

  // Wave(64)-wide shuffle reduction, then cross-wave via LDS.
#pragma unroll
  for (int off = 32; off > 0; off >>= 1)
    acc += __shfl_down(acc, off, 64);

  __shared__ float wsum[THREADS / 64];
  if (lane == 0) wsum[wave] = acc;
  __syncthreads();
  if (t == 0) {
    float sum = 0.0f;
#pragma unroll
    for (int w2 = 0; w2 < THREADS / 64; ++w2) sum += wsum[w2];
    partial[blk] = sum;
  }
}

__global__ void energy_final_kernel(const float* __restrict__ partial,
                                    float* __restrict__ out) {
  const int b = threadIdx.x;
  if (b < B_) {
    float sum = 0.0f;
#pragma unroll
    for (int c2 = 0; c2 < BPB; ++c2)
      sum += partial[(size_t)b * BPB + c2];
    out[b] = sum;
  }
}

extern "C" void kernel_launch(void* const* d_in, const int* in_sizes, int n_in,
                              void* d_out, int out_size, void* d_ws, size_t ws_size,
                              hipStream_t stream) {
  const float* h = (const float*)d_in[0];
  const float* W = (const float*)d_in[1];
  float* partial = (float*)d_ws;      // B_*BPB = 2048 floats
  float* out = (float*)d_out;

  energy_partial_kernel<<<B_ * BPB, THREADS, 0, stream>>>(h, W, partial);
  energy_final_kernel<<<1, 64, 0, stream>>>(partial, out);
}

// Round 8
// 26.307 us; speedup vs baseline: 1.3475x; 1.0638x over previous
//
#include <hip/hip_runtime.h>

// E[b] = sum_n h_n^T (0.5*I + 0.1*W) h_n  — pure streaming reduction.
// B=64, N=65536, I=8. h: (B,N,I) f32, W: (8,8) f32.
// Best-known structure (rounds 1/5): two-kernel deterministic reduction,
// plain cached float4 loads, BPB=32, symmetric-fold SGPR coefficients.
// Ruled out by measurement: nt loads (2x, r4), fused atomic+memset (+9us, r6),
// dense-load shfl pair-exchange (+1.4us, r7), BPB=64 / NPT=4 (neutral, r2).

#define B_ 64
#define N_ 65536
#define I_ 8
#define BPB 32                        // blocks per batch
#define THREADS 256
#define NPB (N_ / BPB)                // 2048 nodes per block
#define NPT (NPB / THREADS)           // 8 nodes per thread

__device__ __forceinline__ float uniform_f(float x) {
  return __int_as_float(__builtin_amdgcn_readfirstlane(__float_as_int(x)));
}

__global__ __launch_bounds__(THREADS) void energy_partial_kernel(
    const float* __restrict__ h, const float* __restrict__ W,
    float* __restrict__ partial) {
  const int blk = blockIdx.x;
  const int b = blk >> 5;             // blk / BPB
  const int chunk = blk & (BPB - 1);  // blk % BPB
  const int t = threadIdx.x;

  // 36 wave-uniform coefficients, forced into SGPRs.
  float c[I_];
  float s[I_][I_];
#pragma unroll
  for (int i = 0; i < I_; ++i) {
    c[i] = uniform_f(0.5f + 0.1f * W[i * I_ + i]);
#pragma unroll
    for (int j = i + 1; j < I_; ++j)
      s[i][j] = uniform_f(0.1f * (W[i * I_ + j] + W[j * I_ + i]));
  }

  const size_t base = (size_t)b * N_ + (size_t)chunk * NPB;
  float acc = 0.0f;

#pragma unroll
  for (int k = 0; k < NPT; ++k) {
    const size_t node = base + (size_t)k * THREADS + (size_t)t;
    const float4* p = reinterpret_cast<const float4*>(h + node * I_);
    float4 a = p[0];
    float4 d = p[1];
    float hv[I_] = {a.x, a.y, a.z, a.w, d.x, d.y, d.z, d.w};
    float e = 0.0f;
#pragma unroll
    for (int i = 0; i < I_; ++i) {
      float ti = c[i] * hv[i];
#pragma unroll
      for (int j = i + 1; j < I_; ++j) ti = fmaf(s[i][j], hv[j], ti);
      e = fmaf(hv[i], ti, e);
    }
    acc += e;
  }

  // Wave(64)-wide shuffle reduction, then cross-wave via LDS.
#pragma unroll
  for (int off = 32; off > 0; off >>= 1)
    acc += __shfl_down(acc, off, 64);

  __shared__ float wsum[THREADS / 64];
  const int wave = t >> 6;
  const int lane = t & 63;
  if (lane == 0) wsum[wave] = acc;
  __syncthreads();
  if (t == 0) {
    float sum = 0.0f;
#pragma unroll
    for (int w = 0; w < THREADS / 64; ++w) sum += wsum[w];
    partial[blk] = sum;
  }
}

__global__ void energy_final_kernel(const float* __restrict__ partial,
                                    float* __restrict__ out) {
  const int b = threadIdx.x;
  if (b < B_) {
    float sum = 0.0f;
#pragma unroll
    for (int c2 = 0; c2 < BPB; ++c2)
      sum += partial[(size_t)b * BPB + c2];
    out[b] = sum;
  }
}

extern "C" void kernel_launch(void* const* d_in, const int* in_sizes, int n_in,
                              void* d_out, int out_size, void* d_ws, size_t ws_size,
                              hipStream_t stream) {
  const float* h = (const float*)d_in[0];
  const float* W = (const float*)d_in[1];
  float* partial = (float*)d_ws;      // B_*BPB = 2048 floats
  float* out = (float*)d_out;

  energy_partial_kernel<<<B_ * BPB, THREADS, 0, stream>>>(h, W, partial);
  energy_final_kernel<<<1, 64, 0, stream>>>(partial, out);
}